// Round 2
// baseline (1399.504 us; speedup 1.0000x reference)
//
#include <hip/hip_runtime.h>
#include <hip/hip_bf16.h>

typedef __bf16 bf16;
typedef __attribute__((ext_vector_type(8))) __bf16 bf16x8;
typedef __attribute__((ext_vector_type(4))) float f32x4;

union BP { unsigned u; bf16 b[2]; };

// ---------------------------------------------------------------------------
// Desc: one 128-output-col GEMM slice.  C[:, coff:coff+128] =
//   A1 @ swz(W1)^T (+ A2 @ swz(W2)^T) + b1 (+ b2)
// W pointers are PRE-SWIZZLED blocks: elem ((kk*8+ct)*64+lane)*8+j holds
// W[ct*16+(lane&15)][kk*32+(lane>>4)*8+j]  -> every B-load is a coalesced
// 1KB wave load.  a2mode: 0=none, 1=bf16, 2=dtype per *flagp (f32 if set).
// (Only used by the output head now; the step GEMMs are fused in fused_k.)
// ---------------------------------------------------------------------------
struct Desc {
  const void* A1; const bf16* W1; int lda1;
  const void* A2; const bf16* W2; int lda2;
  const bf16* b1; const bf16* b2;
  int coff; int a2mode;
};
struct Desc4 { Desc d[4]; };

// NK = number of 32-wide K chunks (4 -> K=128)
template<int NK>
__global__ __launch_bounds__(256) void gemm_k(Desc4 P, bf16* __restrict__ C, int ldc,
                                              int M, const int* __restrict__ flagp)
{
  const Desc d = P.d[blockIdx.y];
  const int lane = threadIdx.x & 63;
  const int w    = threadIdx.x >> 6;
  const int quad = lane >> 4;
  const int lr   = lane & 15;
  const int mbase = blockIdx.x * 128 + w * 32;

  __shared__ bf16 lds[128 * 136];   // padded stride 136 (272B rows, 16B aligned)

  f32x4 acc[2][8];
#pragma unroll
  for (int i = 0; i < 2; ++i)
#pragma unroll
    for (int j = 0; j < 8; ++j) acc[i][j] = (f32x4){0.f, 0.f, 0.f, 0.f};

  long r0 = mbase + lr;      if (r0 >= M) r0 = M - 1;
  long r1 = mbase + 16 + lr; if (r1 >= M) r1 = M - 1;

  // ---- A1 pass (A1 is always bf16) ----
  {
    const bf16* A = (const bf16*)d.A1;
    const int lda = d.lda1;
#pragma unroll
    for (int kk = 0; kk < NK; ++kk) {
      const int kc = kk * 32 + quad * 8;
      bf16x8 a0 = *(const bf16x8*)(A + r0 * lda + kc);
      bf16x8 a1 = *(const bf16x8*)(A + r1 * lda + kc);
#pragma unroll
      for (int ct = 0; ct < 8; ++ct) {
        bf16x8 b = *(const bf16x8*)(d.W1 + ((size_t)(kk * 8 + ct) * 64 + lane) * 8);
        acc[0][ct] = __builtin_amdgcn_mfma_f32_16x16x32_bf16(a0, b, acc[0][ct], 0, 0, 0);
        acc[1][ct] = __builtin_amdgcn_mfma_f32_16x16x32_bf16(a1, b, acc[1][ct], 0, 0, 0);
      }
    }
  }
  // ---- A2 pass ----
  if (d.a2mode != 0) {
    const int lda = d.lda2;
    const bool f32 = (d.a2mode == 2) && (*flagp != 0);
    if (f32) {
      const float* A = (const float*)d.A2;
#pragma unroll
      for (int kk = 0; kk < NK; ++kk) {
        const int kc = kk * 32 + quad * 8;
        f32x4 x0 = *(const f32x4*)(A + r0 * lda + kc);
        f32x4 x1 = *(const f32x4*)(A + r0 * lda + kc + 4);
        f32x4 y0 = *(const f32x4*)(A + r1 * lda + kc);
        f32x4 y1 = *(const f32x4*)(A + r1 * lda + kc + 4);
        bf16x8 a0, a1;
#pragma unroll
        for (int i = 0; i < 4; ++i) {
          a0[i] = (bf16)x0[i]; a0[i + 4] = (bf16)x1[i];
          a1[i] = (bf16)y0[i]; a1[i + 4] = (bf16)y1[i];
        }
#pragma unroll
        for (int ct = 0; ct < 8; ++ct) {
          bf16x8 b = *(const bf16x8*)(d.W2 + ((size_t)(kk * 8 + ct) * 64 + lane) * 8);
          acc[0][ct] = __builtin_amdgcn_mfma_f32_16x16x32_bf16(a0, b, acc[0][ct], 0, 0, 0);
          acc[1][ct] = __builtin_amdgcn_mfma_f32_16x16x32_bf16(a1, b, acc[1][ct], 0, 0, 0);
        }
      }
    } else {
      const bf16* A = (const bf16*)d.A2;
#pragma unroll
      for (int kk = 0; kk < NK; ++kk) {
        const int kc = kk * 32 + quad * 8;
        bf16x8 a0 = *(const bf16x8*)(A + r0 * lda + kc);
        bf16x8 a1 = *(const bf16x8*)(A + r1 * lda + kc);
#pragma unroll
        for (int ct = 0; ct < 8; ++ct) {
          bf16x8 b = *(const bf16x8*)(d.W2 + ((size_t)(kk * 8 + ct) * 64 + lane) * 8);
          acc[0][ct] = __builtin_amdgcn_mfma_f32_16x16x32_bf16(a0, b, acc[0][ct], 0, 0, 0);
          acc[1][ct] = __builtin_amdgcn_mfma_f32_16x16x32_bf16(a1, b, acc[1][ct], 0, 0, 0);
        }
      }
    }
  }

  // ---- epilogue: acc -> LDS (C/D layout: col=lr, row16 = quad*4+reg) ----
#pragma unroll
  for (int ct = 0; ct < 8; ++ct) {
    const int nl = ct * 16 + lr;
    float bv = 0.f;
    if (d.b1) bv += (float)d.b1[nl];
    if (d.b2) bv += (float)d.b2[nl];
#pragma unroll
    for (int rt = 0; rt < 2; ++rt) {
      const int rowb = w * 32 + rt * 16 + quad * 4;
#pragma unroll
      for (int r = 0; r < 4; ++r)
        lds[(rowb + r) * 136 + nl] = (bf16)(acc[rt][ct][r] + bv);
    }
  }
  __syncthreads();
  // coalesced readback + store: 16 threads cover one 256B row segment
  const int tr = threadIdx.x >> 4;          // 0..15
  const int tc = (threadIdx.x & 15) * 8;    // col
#pragma unroll
  for (int i = 0; i < 8; ++i) {
    const int row = i * 16 + tr;
    const int grow = blockIdx.x * 128 + row;
    if (grow < M) {
      bf16x8 v = *(const bf16x8*)(lds + row * 136 + tc);
      *(bf16x8*)(C + (size_t)grow * ldc + d.coff + tc) = v;
    }
  }
}

// ---------------------------------------------------------------------------
// fused per-step GEMM:  replaces gemm_k<17> (a = aggH @ Wcat) + the 4-slice
// GRU-gate GEMM.  Per 128-row tile:
//   pass1: a-tile = big[:,0:544] @ swz(Wcat)^T      (K=544, acc f32)
//          -> staged to LDS as bf16
//   each wave re-reads ITS OWN 32 rows from LDS as MFMA A-fragments (regs),
//   loads its hb fragments once (regs), then computes 4 output slices:
//     s0: a@ih0 + hb@hh0 + bih[0:128]+bhh[0:128]    -> big[:,  0:128]  (sr)
//     s1: a@ih1 + hb@hh1 + bih[128:256]+bhh[128:256]-> big[:,128:256]  (sz)
//     s2: a@ihn + bih[256:384]                      -> big[:,256:384]  (in)
//     s3: hb@hhn + bhh[256:384]                     -> big[:,384:512]  (hn)
// In-place hazard is tile-local only: big rows are fully consumed into
// regs/LDS before the slice stores overwrite them (clamped rows only occur
// inside the last tile itself).
// Kills the a[N,128] HBM round-trip and the 3x re-reads of a/hb, and gives
// each wave 656 MFMAs (vs 128) for latency tolerance.
// ---------------------------------------------------------------------------
__global__ __launch_bounds__(256, 3) void fused_k(bf16* __restrict__ big,
                                                  const bf16* __restrict__ hbp,
                                                  const bf16* __restrict__ wb,
                                                  int M)
{
  const int lane = threadIdx.x & 63;
  const int w    = threadIdx.x >> 6;
  const int quad = lane >> 4;
  const int lr   = lane & 15;
  const int mbase = blockIdx.x * 128 + w * 32;

  __shared__ bf16 lds[128 * 136];

  const bf16* wcat = wb;
  const bf16* blk  = wb + 69632;
  const bf16 *ih0 = blk,             *ih1 = blk + 16384, *ihn = blk + 2 * 16384;
  const bf16 *hh0 = blk + 3 * 16384, *hh1 = blk + 4 * 16384, *hhn = blk + 5 * 16384;
  const bf16 *bih = wb + 217088, *bhh = wb + 217472;

  long r0 = mbase + lr;      if (r0 >= M) r0 = M - 1;
  long r1 = mbase + 16 + lr; if (r1 >= M) r1 = M - 1;

  // ---- pass 1: a-tile (K=544) ----
  f32x4 acc[2][8];
#pragma unroll
  for (int i = 0; i < 2; ++i)
#pragma unroll
    for (int j = 0; j < 8; ++j) acc[i][j] = (f32x4){0.f, 0.f, 0.f, 0.f};
#pragma unroll
  for (int kk = 0; kk < 17; ++kk) {
    const int kc = kk * 32 + quad * 8;
    bf16x8 a0 = *(const bf16x8*)(big + r0 * 544 + kc);
    bf16x8 a1 = *(const bf16x8*)(big + r1 * 544 + kc);
#pragma unroll
    for (int ct = 0; ct < 8; ++ct) {
      bf16x8 b = *(const bf16x8*)(wcat + ((size_t)(kk * 8 + ct) * 64 + lane) * 8);
      acc[0][ct] = __builtin_amdgcn_mfma_f32_16x16x32_bf16(a0, b, acc[0][ct], 0, 0, 0);
      acc[1][ct] = __builtin_amdgcn_mfma_f32_16x16x32_bf16(a1, b, acc[1][ct], 0, 0, 0);
    }
  }
  // stage a-tile to LDS (bf16), no bias
#pragma unroll
  for (int ct = 0; ct < 8; ++ct) {
    const int nl = ct * 16 + lr;
#pragma unroll
    for (int rt = 0; rt < 2; ++rt) {
      const int rowb = w * 32 + rt * 16 + quad * 4;
#pragma unroll
      for (int r = 0; r < 4; ++r)
        lds[(rowb + r) * 136 + nl] = (bf16)acc[rt][ct][r];
    }
  }
  // each wave reads only its OWN rows back -> no barrier needed here
  bf16x8 af[2][4], hf[2][4];
#pragma unroll
  for (int kk = 0; kk < 4; ++kk) {
    af[0][kk] = *(const bf16x8*)(lds + (w * 32 + lr) * 136 + kk * 32 + quad * 8);
    af[1][kk] = *(const bf16x8*)(lds + (w * 32 + 16 + lr) * 136 + kk * 32 + quad * 8);
    hf[0][kk] = *(const bf16x8*)(hbp + r0 * 128 + kk * 32 + quad * 8);
    hf[1][kk] = *(const bf16x8*)(hbp + r1 * 128 + kk * 32 + quad * 8);
  }

  const int tr = threadIdx.x >> 4;
  const int tc = (threadIdx.x & 15) * 8;

  // ---- 4 output slices from registers ----
#pragma unroll
  for (int s = 0; s < 4; ++s) {
    const bf16* W1 = (s == 0) ? ih0 : (s == 1) ? ih1 : (s == 2) ? ihn : hhn;
    const bf16* W2 = (s == 0) ? hh0 : (s == 1) ? hh1 : nullptr;
    const bf16* B1 = (s == 0) ? bih : (s == 1) ? bih + 128 : (s == 2) ? bih + 256 : bhh + 256;
    const bf16* B2 = (s == 0) ? bhh : (s == 1) ? bhh + 128 : nullptr;

    f32x4 c2[2][8];
#pragma unroll
    for (int i = 0; i < 2; ++i)
#pragma unroll
      for (int j = 0; j < 8; ++j) c2[i][j] = (f32x4){0.f, 0.f, 0.f, 0.f};

#pragma unroll
    for (int kk = 0; kk < 4; ++kk) {
#pragma unroll
      for (int ct = 0; ct < 8; ++ct) {
        bf16x8 b = *(const bf16x8*)(W1 + ((size_t)(kk * 8 + ct) * 64 + lane) * 8);
        if (s < 3) {
          c2[0][ct] = __builtin_amdgcn_mfma_f32_16x16x32_bf16(af[0][kk], b, c2[0][ct], 0, 0, 0);
          c2[1][ct] = __builtin_amdgcn_mfma_f32_16x16x32_bf16(af[1][kk], b, c2[1][ct], 0, 0, 0);
        } else {
          c2[0][ct] = __builtin_amdgcn_mfma_f32_16x16x32_bf16(hf[0][kk], b, c2[0][ct], 0, 0, 0);
          c2[1][ct] = __builtin_amdgcn_mfma_f32_16x16x32_bf16(hf[1][kk], b, c2[1][ct], 0, 0, 0);
        }
        if (s < 2) {
          bf16x8 b2 = *(const bf16x8*)(W2 + ((size_t)(kk * 8 + ct) * 64 + lane) * 8);
          c2[0][ct] = __builtin_amdgcn_mfma_f32_16x16x32_bf16(hf[0][kk], b2, c2[0][ct], 0, 0, 0);
          c2[1][ct] = __builtin_amdgcn_mfma_f32_16x16x32_bf16(hf[1][kk], b2, c2[1][ct], 0, 0, 0);
        }
      }
    }
    // barrier: previous slice's cross-wave LDS readback (or pass1 a-tile use)
    // must finish before this slice overwrites LDS
    __syncthreads();
#pragma unroll
    for (int ct = 0; ct < 8; ++ct) {
      const int nl = ct * 16 + lr;
      float bv = (float)B1[nl];
      if (s < 2) bv += (float)B2[nl];
#pragma unroll
      for (int rt = 0; rt < 2; ++rt) {
        const int rowb = w * 32 + rt * 16 + quad * 4;
#pragma unroll
        for (int r = 0; r < 4; ++r)
          lds[(rowb + r) * 136 + nl] = (bf16)(c2[rt][ct][r] + bv);
      }
    }
    __syncthreads();
#pragma unroll
    for (int i = 0; i < 8; ++i) {
      const int row = i * 16 + tr;
      const int grow = blockIdx.x * 128 + row;
      if (grow < M) {
        bf16x8 v = *(const bf16x8*)(lds + row * 136 + tc);
        *(bf16x8*)(big + (size_t)grow * 512 + s * 128 + tc) = v;
      }
    }
  }
}

// ---------------------------------------------------------------------------
// dtype detect (bf16 features never have |x|>=256; fp32 low halves do)
// ---------------------------------------------------------------------------
__global__ __launch_bounds__(256) void detect_k(const unsigned short* __restrict__ f,
                                                int n16, int* __restrict__ flag)
{
  int i = blockIdx.x * 256 + threadIdx.x;
  int bad = 0;
  for (int j = i; j < n16; j += 256 * 1024) {
    int ex = (f[j] >> 7) & 0xFF;
    if (ex >= 0x87) bad = 1;
  }
  if (bad) atomicAdd(flag, 1);
}

__global__ __launch_bounds__(256) void feat_k(const void* __restrict__ src,
                                              bf16* __restrict__ hb, int n,
                                              const int* __restrict__ flag)
{
  int i = blockIdx.x * 256 + threadIdx.x;
  if (i >= n) return;
  if (*flag) hb[i] = (bf16)((const float*)src)[i];
  else       hb[i] = ((const bf16*)src)[i];
}

// ---------------------------------------------------------------------------
// weight canonicalize + swizzle.  wb layout (elements):
//   [0, 69632)        WcatX swz, NK=17: (n,k): k<512 -> W_et[k>>7][n][k&127],
//                     512..515 -> b_et[k-512][n], else 0
//   [69632 + blk*16384) 9 swz 128x128 blocks: ih0,ih1,ihn,hh0,hh1,hhn,iwa,iwb,jw
//   [217088) b_ih(384) b_hh(384) i_b(128) j_b(128)   -> total 218112
// ---------------------------------------------------------------------------
__global__ __launch_bounds__(256) void cvtw_k(
    const void* w_et, const void* b_et, const void* w_ih, const void* b_ih,
    const void* w_hh, const void* b_hh, const void* i_w, const void* i_b,
    const void* j_w, const void* j_b, bf16* __restrict__ wb,
    const int* __restrict__ flagp)
{
  int i = blockIdx.x * 256 + threadIdx.x;
  if (i >= 218112) return;
  const bool f32 = (*flagp != 0);
  auto rd = [&](const void* p, int idx) -> float {
    return f32 ? ((const float*)p)[idx] : (float)((const bf16*)p)[idx];
  };
  float v;
  if (i < 69632) {
    int e = i, j = e & 7, lane = (e >> 3) & 63, ct = (e >> 9) & 7, kk = e >> 12;
    int n = ct * 16 + (lane & 15), k = kk * 32 + (lane >> 4) * 8 + j;
    if (k < 512)      v = rd(w_et, (k >> 7) * 16384 + n * 128 + (k & 127));
    else if (k < 516) v = rd(b_et, (k - 512) * 128 + n);
    else              v = 0.f;
  } else if (i < 217088) {
    int blk = (i - 69632) >> 14, e = (i - 69632) & 16383;
    int j = e & 7, lane = (e >> 3) & 63, ct = (e >> 9) & 7, kk = e >> 12;
    int n = ct * 16 + (lane & 15), k = kk * 32 + (lane >> 4) * 8 + j;
    const void* src; int idx;
    switch (blk) {
      case 0: src = w_ih; idx = n * 128 + k; break;
      case 1: src = w_ih; idx = (128 + n) * 128 + k; break;
      case 2: src = w_ih; idx = (256 + n) * 128 + k; break;
      case 3: src = w_hh; idx = n * 128 + k; break;
      case 4: src = w_hh; idx = (128 + n) * 128 + k; break;
      case 5: src = w_hh; idx = (256 + n) * 128 + k; break;
      case 6: src = i_w;  idx = n * 256 + k; break;
      case 7: src = i_w;  idx = n * 256 + 128 + k; break;
      default: src = j_w; idx = n * 128 + k; break;
    }
    v = rd(src, idx);
  } else {
    int o = i - 217088;
    if (o < 384)      v = rd(b_ih, o);
    else if (o < 768) v = rd(b_hh, o - 384);
    else if (o < 896) v = rd(i_b, o - 768);
    else              v = rd(j_b, o - 896);
  }
  wb[i] = (bf16)v;
}

// ---------------------------------------------------------------------------
// CSR keyed by dst*4 + etype  (dst/etype constant across steps)
// ---------------------------------------------------------------------------
__global__ __launch_bounds__(256) void hist_k(const int* __restrict__ dst,
                                              const int* __restrict__ ety,
                                              int* __restrict__ deg, int E)
{
  int e = blockIdx.x * 256 + threadIdx.x;
  if (e < E) atomicAdd(&deg[dst[e] * 4 + ety[e]], 1);
}

__global__ __launch_bounds__(512) void scan1_k(const int* __restrict__ deg, int* __restrict__ rp,
                                               int* __restrict__ part, int n)
{
  __shared__ int buf[512];
  int i = blockIdx.x * 512 + threadIdx.x;
  int v = (i < n) ? deg[i] : 0;
  buf[threadIdx.x] = v;
  __syncthreads();
#pragma unroll
  for (int off = 1; off < 512; off <<= 1) {
    int t = 0;
    if (threadIdx.x >= off) t = buf[threadIdx.x - off];
    __syncthreads();
    buf[threadIdx.x] += t;
    __syncthreads();
  }
  if (i < n) rp[i] = buf[threadIdx.x] - v;
  if (threadIdx.x == 511) part[blockIdx.x] = buf[511];
}

__global__ __launch_bounds__(1024) void scan2_k(int* __restrict__ part, int nb, int* __restrict__ total)
{
  __shared__ int buf[1024];
  int t0 = threadIdx.x;
  int v = (t0 < nb) ? part[t0] : 0;
  buf[t0] = v;
  __syncthreads();
#pragma unroll
  for (int off = 1; off < 1024; off <<= 1) {
    int t = 0;
    if (t0 >= off) t = buf[t0 - off];
    __syncthreads();
    buf[t0] += t;
    __syncthreads();
  }
  if (t0 < nb) part[t0] = buf[t0] - v;
  if (t0 == 1023) *total = buf[1023];
}

__global__ __launch_bounds__(512) void scan3_k(int* __restrict__ rp, const int* __restrict__ part, int n)
{
  int i = blockIdx.x * 512 + threadIdx.x;
  if (i < n) rp[i] += part[blockIdx.x];
}

__global__ __launch_bounds__(256) void fill_k(const int* __restrict__ src, const int* __restrict__ dst,
                                              const int* __restrict__ ety, const int* __restrict__ rp,
                                              int* __restrict__ fil, int* __restrict__ bkt, int E)
{
  int e = blockIdx.x * 256 + threadIdx.x;
  if (e < E) {
    int key = dst[e] * 4 + ety[e];
    int pos = rp[key] + atomicAdd(&fil[key], 1);
    bkt[pos] = src[e];
  }
}

// ---------------------------------------------------------------------------
// aggregate raw h per (dst, etype) -> aggH[n, 544]:
//   cols k*128+d = sum of h[src][d] over etype-k in-edges; 512+k = deg_k; rest 0
// wave per node; lane owns 2 dims (one dword per edge-row read).
// Edge loop is batched 4-wide (clamped indices + predicated accumulate) so
// each wave keeps 4 independent row-gathers in flight instead of a serial
// bkt->h dependency chain per edge (agg was latency-bound: 23% HBM, 20% VALU).
// ---------------------------------------------------------------------------
__global__ __launch_bounds__(256) void agg_k(const bf16* __restrict__ hb,
                                             const int* __restrict__ rp,
                                             const int* __restrict__ bkt,
                                             bf16* __restrict__ aggH, int N)
{
  const int lane = threadIdx.x & 63;
  const int n = blockIdx.x * 4 + (threadIdx.x >> 6);
  if (n >= N) return;
  const unsigned* hp = (const unsigned*)hb;
  unsigned* outp = (unsigned*)aggH + (size_t)n * 272;
  int d0, d1, d2, d3;
  int prev = rp[n * 4];
#pragma unroll
  for (int k = 0; k < 4; ++k) {
    int nxt = rp[n * 4 + k + 1];
    const int last = nxt - 1;
    float a0 = 0.f, a1 = 0.f;
    for (int base = prev; base < nxt; base += 4) {
      const int i1 = base + 1, i2 = base + 2, i3 = base + 3;
      // batch the index loads (independent, uniform addresses)
      int b0 = bkt[base];
      int b1 = bkt[i1 < nxt ? i1 : last];
      int b2 = bkt[i2 < nxt ? i2 : last];
      int b3 = bkt[i3 < nxt ? i3 : last];
      // 4 independent coalesced 256B row-gathers in flight per wave
      unsigned u0 = hp[(size_t)b0 * 64 + lane];
      unsigned u1 = hp[(size_t)b1 * 64 + lane];
      unsigned u2 = hp[(size_t)b2 * 64 + lane];
      unsigned u3 = hp[(size_t)b3 * 64 + lane];
      BP t0, t1, t2, t3;
      t0.u = u0; t1.u = u1; t2.u = u2; t3.u = u3;
      a0 += (float)t0.b[0];
      a1 += (float)t0.b[1];
      a0 += (i1 < nxt) ? (float)t1.b[0] : 0.f;
      a1 += (i1 < nxt) ? (float)t1.b[1] : 0.f;
      a0 += (i2 < nxt) ? (float)t2.b[0] : 0.f;
      a1 += (i2 < nxt) ? (float)t2.b[1] : 0.f;
      a0 += (i3 < nxt) ? (float)t3.b[0] : 0.f;
      a1 += (i3 < nxt) ? (float)t3.b[1] : 0.f;
    }
    BP o; o.b[0] = (bf16)a0; o.b[1] = (bf16)a1;
    outp[k * 64 + lane] = o.u;
    int dk = nxt - prev;
    if (k == 0) d0 = dk; else if (k == 1) d1 = dk; else if (k == 2) d2 = dk; else d3 = dk;
    prev = nxt;
  }
  if (lane < 16) {
    BP o; o.b[0] = (bf16)0.f; o.b[1] = (bf16)0.f;
    if (lane == 0) { o.b[0] = (bf16)(float)d0; o.b[1] = (bf16)(float)d1; }
    if (lane == 1) { o.b[0] = (bf16)(float)d2; o.b[1] = (bf16)(float)d3; }
    outp[256 + lane] = o.u;
  }
}

// ---------------------------------------------------------------------------
// GRU finish: G[n,512] = [srz(256) | in(128) | hn(128)];  h' -> hb (bf16)
// ---------------------------------------------------------------------------
__global__ __launch_bounds__(256) void gru_k(const bf16* __restrict__ G,
                                             bf16* __restrict__ hb, int N)
{
  int i = blockIdx.x * 256 + threadIdx.x;    // over N*64 (bf16x2 per thread)
  if (i >= N * 64) return;
  int n = i >> 6, l = i & 63;
  const unsigned* g = (const unsigned*)G + (size_t)n * 256;
  unsigned* h = (unsigned*)hb + (size_t)n * 64;
  BP sr, sz, in_, hn, hv, o;
  sr.u = g[l]; sz.u = g[64 + l]; in_.u = g[128 + l]; hn.u = g[192 + l];
  hv.u = h[l];
#pragma unroll
  for (int q = 0; q < 2; ++q) {
    float r = 1.f / (1.f + expf(-(float)sr.b[q]));
    float z = 1.f / (1.f + expf(-(float)sz.b[q]));
    float nn = tanhf((float)in_.b[q] + r * (float)hn.b[q]);
    o.b[q] = (bf16)((1.f - z) * nn + z * (float)hv.b[q]);
  }
  h[l] = o.u;
}

// head: G[n,256] = [gl | u];  out = sigmoid(gl) * u
__global__ __launch_bounds__(256) void head_k(const bf16* __restrict__ G,
                                              void* __restrict__ out, int N,
                                              const int* __restrict__ flag)
{
  int i = blockIdx.x * 256 + threadIdx.x;    // over N*64
  if (i >= N * 64) return;
  int n = i >> 6, l = i & 63;
  const unsigned* g = (const unsigned*)G + (size_t)n * 128;
  BP gl, uu;
  gl.u = g[l]; uu.u = g[64 + l];
  float v0 = (float)uu.b[0] / (1.f + expf(-(float)gl.b[0]));
  float v1 = (float)uu.b[1] / (1.f + expf(-(float)gl.b[1]));
  if (*flag) {
    ((float*)out)[(size_t)n * 128 + 2 * l]     = v0;
    ((float*)out)[(size_t)n * 128 + 2 * l + 1] = v1;
  } else {
    BP o; o.b[0] = (bf16)v0; o.b[1] = (bf16)v1;
    ((unsigned*)out)[(size_t)n * 64 + l] = o.u;
  }
}

// ---------------------------------------------------------------------------
extern "C" void kernel_launch(void* const* d_in, const int* in_sizes, int n_in,
                              void* d_out, int out_size, void* d_ws, size_t ws_size,
                              hipStream_t stream)
{
  const void* feat = d_in[0];
  const int*  src  = (const int*)d_in[1];
  const int*  dst  = (const int*)d_in[2];
  const int*  ety  = (const int*)d_in[3];

  const int N = in_sizes[0] / 128;   // 100000
  const int E = in_sizes[1];         // 1600000
  const int total = N * 128;

  // ---- workspace (~145 MB) ----
  char* p = (char*)d_ws;
  auto alloc = [&](size_t bytes) -> char* {
    char* q = p;
    p += (bytes + 255) & ~(size_t)255;
    return q;
  };
  bf16* big  = (bf16*)alloc((size_t)N * 544 * 2);   // aggH [N,544] / G [N,512]
  bf16* hb   = (bf16*)alloc((size_t)total * 2);     // h (bf16)
  bf16* wb   = (bf16*)alloc(218112 * 2);
  int*  rp   = (int*) alloc(((size_t)4 * N + 1) * 4);
  int*  deg  = (int*) alloc((size_t)4 * N * 4);     // reused as fill counters
  int*  bkt  = (int*) alloc((size_t)E * 4);
  int*  part = (int*) alloc(1024 * 4);
  int*  flag = (int*) alloc(64);

  // wb offsets
  const int oBlk = 69632;
  const bf16 *iwa = wb + oBlk + 6 * 16384, *iwb = wb + oBlk + 7 * 16384,
             *jw  = wb + oBlk + 8 * 16384;
  const bf16 *ib = wb + 217856, *jb = wb + 217984;

  const int gE  = (E + 255) / 256;
  const int gT  = (total + 255) / 256;
  const int gM  = (N + 127) / 128;
  const int n4  = 4 * N;
  const int gS  = (n4 + 511) / 512;
  const int gH  = (N * 64 + 255) / 256;

  // ---- dtype detect + canonicalize ----
  hipMemsetAsync(flag, 0, 4, stream);
  detect_k<<<1024, 256, 0, stream>>>((const unsigned short*)feat, 2000000, flag);
  feat_k<<<gT, 256, 0, stream>>>(feat, hb, total, flag);
  cvtw_k<<<(218112 + 255) / 256, 256, 0, stream>>>(
      d_in[4], d_in[5], d_in[6], d_in[7], d_in[8],
      d_in[9], d_in[10], d_in[11], d_in[12], d_in[13], wb, flag);

  // ---- CSR build ----
  hipMemsetAsync(deg, 0, (size_t)n4 * 4, stream);
  hist_k<<<gE, 256, 0, stream>>>(dst, ety, deg, E);
  scan1_k<<<gS, 512, 0, stream>>>(deg, rp, part, n4);
  scan2_k<<<1, 1024, 0, stream>>>(part, gS, rp + n4);
  scan3_k<<<gS, 512, 0, stream>>>(rp, part, n4);
  hipMemsetAsync(deg, 0, (size_t)n4 * 4, stream);
  fill_k<<<gE, 256, 0, stream>>>(src, dst, ety, rp, deg, bkt, E);

  // ---- head GEMM descriptors ----
  Desc4 Ph = {};
  Ph.d[0] = { hb, iwa, 128, feat, iwb, 128, ib, nullptr, 0,   2 };
  Ph.d[1] = { hb, jw,  128, nullptr, nullptr, 0, jb, nullptr, 128, 0 };

  for (int step = 0; step < 3; ++step) {
    agg_k<<<(N + 3) / 4, 256, 0, stream>>>(hb, rp, bkt, big, N);
    fused_k<<<gM, 256, 0, stream>>>(big, hb, wb, N);
    gru_k<<<gH, 256, 0, stream>>>(big, hb, N);
  }

  // ---- head ----
  gemm_k<4><<<dim3(gM, 2), 256, 0, stream>>>(Ph, big, 256, N, flag);
  head_k<<<gH, 256, 0, stream>>>(big, d_out, N, flag);
}

// Round 3
// 1294.522 us; speedup vs baseline: 1.0811x; 1.0811x over previous
//
#include <hip/hip_runtime.h>
#include <hip/hip_bf16.h>

typedef __bf16 bf16;
typedef __attribute__((ext_vector_type(8))) __bf16 bf16x8;
typedef __attribute__((ext_vector_type(4))) float f32x4;

union BP { unsigned u; bf16 b[2]; };

// ---------------------------------------------------------------------------
// Desc: one 128-output-col GEMM slice.  C[:, coff:coff+128] =
//   A1 @ swz(W1)^T (+ A2 @ swz(W2)^T) + b1 (+ b2)
// W pointers are PRE-SWIZZLED blocks: elem ((kk*8+ct)*64+lane)*8+j holds
// W[ct*16+(lane&15)][kk*32+(lane>>4)*8+j]  -> every B-load is a coalesced
// 1KB wave load.  a2mode: 0=none, 1=bf16, 2=dtype per *flagp (f32 if set).
// (Only the output head uses this now; step GEMMs+GRU live in fused_k.)
// ---------------------------------------------------------------------------
struct Desc {
  const void* A1; const bf16* W1; int lda1;
  const void* A2; const bf16* W2; int lda2;
  const bf16* b1; const bf16* b2;
  int coff; int a2mode;
};
struct Desc4 { Desc d[4]; };

// NK = number of 32-wide K chunks (4 -> K=128)
template<int NK>
__global__ __launch_bounds__(256) void gemm_k(Desc4 P, bf16* __restrict__ C, int ldc,
                                              int M, const int* __restrict__ flagp)
{
  const Desc d = P.d[blockIdx.y];
  const int lane = threadIdx.x & 63;
  const int w    = threadIdx.x >> 6;
  const int quad = lane >> 4;
  const int lr   = lane & 15;
  const int mbase = blockIdx.x * 128 + w * 32;

  __shared__ bf16 lds[128 * 136];   // padded stride 136 (272B rows, 16B aligned)

  f32x4 acc[2][8];
#pragma unroll
  for (int i = 0; i < 2; ++i)
#pragma unroll
    for (int j = 0; j < 8; ++j) acc[i][j] = (f32x4){0.f, 0.f, 0.f, 0.f};

  long r0 = mbase + lr;      if (r0 >= M) r0 = M - 1;
  long r1 = mbase + 16 + lr; if (r1 >= M) r1 = M - 1;

  // ---- A1 pass (A1 is always bf16) ----
  {
    const bf16* A = (const bf16*)d.A1;
    const int lda = d.lda1;
#pragma unroll
    for (int kk = 0; kk < NK; ++kk) {
      const int kc = kk * 32 + quad * 8;
      bf16x8 a0 = *(const bf16x8*)(A + r0 * lda + kc);
      bf16x8 a1 = *(const bf16x8*)(A + r1 * lda + kc);
#pragma unroll
      for (int ct = 0; ct < 8; ++ct) {
        bf16x8 b = *(const bf16x8*)(d.W1 + ((size_t)(kk * 8 + ct) * 64 + lane) * 8);
        acc[0][ct] = __builtin_amdgcn_mfma_f32_16x16x32_bf16(a0, b, acc[0][ct], 0, 0, 0);
        acc[1][ct] = __builtin_amdgcn_mfma_f32_16x16x32_bf16(a1, b, acc[1][ct], 0, 0, 0);
      }
    }
  }
  // ---- A2 pass ----
  if (d.a2mode != 0) {
    const int lda = d.lda2;
    const bool f32 = (d.a2mode == 2) && (*flagp != 0);
    if (f32) {
      const float* A = (const float*)d.A2;
#pragma unroll
      for (int kk = 0; kk < NK; ++kk) {
        const int kc = kk * 32 + quad * 8;
        f32x4 x0 = *(const f32x4*)(A + r0 * lda + kc);
        f32x4 x1 = *(const f32x4*)(A + r0 * lda + kc + 4);
        f32x4 y0 = *(const f32x4*)(A + r1 * lda + kc);
        f32x4 y1 = *(const f32x4*)(A + r1 * lda + kc + 4);
        bf16x8 a0, a1;
#pragma unroll
        for (int i = 0; i < 4; ++i) {
          a0[i] = (bf16)x0[i]; a0[i + 4] = (bf16)x1[i];
          a1[i] = (bf16)y0[i]; a1[i + 4] = (bf16)y1[i];
        }
#pragma unroll
        for (int ct = 0; ct < 8; ++ct) {
          bf16x8 b = *(const bf16x8*)(d.W2 + ((size_t)(kk * 8 + ct) * 64 + lane) * 8);
          acc[0][ct] = __builtin_amdgcn_mfma_f32_16x16x32_bf16(a0, b, acc[0][ct], 0, 0, 0);
          acc[1][ct] = __builtin_amdgcn_mfma_f32_16x16x32_bf16(a1, b, acc[1][ct], 0, 0, 0);
        }
      }
    } else {
      const bf16* A = (const bf16*)d.A2;
#pragma unroll
      for (int kk = 0; kk < NK; ++kk) {
        const int kc = kk * 32 + quad * 8;
        bf16x8 a0 = *(const bf16x8*)(A + r0 * lda + kc);
        bf16x8 a1 = *(const bf16x8*)(A + r1 * lda + kc);
#pragma unroll
        for (int ct = 0; ct < 8; ++ct) {
          bf16x8 b = *(const bf16x8*)(d.W2 + ((size_t)(kk * 8 + ct) * 64 + lane) * 8);
          acc[0][ct] = __builtin_amdgcn_mfma_f32_16x16x32_bf16(a0, b, acc[0][ct], 0, 0, 0);
          acc[1][ct] = __builtin_amdgcn_mfma_f32_16x16x32_bf16(a1, b, acc[1][ct], 0, 0, 0);
        }
      }
    }
  }

  // ---- epilogue: acc -> LDS (C/D layout: col=lr, row16 = quad*4+reg) ----
#pragma unroll
  for (int ct = 0; ct < 8; ++ct) {
    const int nl = ct * 16 + lr;
    float bv = 0.f;
    if (d.b1) bv += (float)d.b1[nl];
    if (d.b2) bv += (float)d.b2[nl];
#pragma unroll
    for (int rt = 0; rt < 2; ++rt) {
      const int rowb = w * 32 + rt * 16 + quad * 4;
#pragma unroll
      for (int r = 0; r < 4; ++r)
        lds[(rowb + r) * 136 + nl] = (bf16)(acc[rt][ct][r] + bv);
    }
  }
  __syncthreads();
  // coalesced readback + store: 16 threads cover one 256B row segment
  const int tr = threadIdx.x >> 4;          // 0..15
  const int tc = (threadIdx.x & 15) * 8;    // col
#pragma unroll
  for (int i = 0; i < 8; ++i) {
    const int row = i * 16 + tr;
    const int grow = blockIdx.x * 128 + row;
    if (grow < M) {
      bf16x8 v = *(const bf16x8*)(lds + row * 136 + tc);
      *(bf16x8*)(C + (size_t)grow * ldc + d.coff + tc) = v;
    }
  }
}

// ---------------------------------------------------------------------------
// fully-fused step kernel: a = aggH @ Wcat  ->  4 GRU gate GEMMs  ->  GRU
// nonlinearity -> h' written in place to hb.  Per 128-row tile:
//   pass1: a-tile = big[:,0:544] @ swz(Wcat)^T (K=544, f32 acc) -> LDS bf16
//   af    = wave's own 32 a-rows back from LDS (A-fragment layout, regs)
//   LDS rows then overwritten with the wave's h-tile (for C/D-layout hv reads)
//   per 32-col chunk: all 4 gate slices accumulated (4x16 f32 regs, element-
//   wise aligned in C/D layout) -> GRU math in registers, hv from LDS,
//   h' written back into the same LDS slot -> one barrier -> coalesced store.
// All LDS access is wave-private (rows w*32..w*32+31) until the final barrier.
// In-place hb hazard: each block reads hb only for its own tile rows (r0/r1
// clamp to M-1 which is inside the last tile), so the h' store is tile-local.
// VGPR note: __launch_bounds__(256) ONLY - round-2's (256,3) made the
// allocator target 85 VGPRs and destroyed the MFMA pipeline (84 VGPR, 253us).
// Live set here is ~150-180 (af 32 + hf 32 + chunk accs 64 + transients).
// ---------------------------------------------------------------------------
__global__ __launch_bounds__(256) void fused_k(const bf16* __restrict__ big,
                                               bf16* __restrict__ hbp,
                                               const bf16* __restrict__ wb,
                                               int M)
{
  const int lane = threadIdx.x & 63;
  const int w    = threadIdx.x >> 6;
  const int quad = lane >> 4;
  const int lr   = lane & 15;
  const int mbase = blockIdx.x * 128 + w * 32;

  __shared__ bf16 lds[128 * 136];

  const bf16* wcat = wb;
  const bf16* blk  = wb + 69632;
  const bf16 *ih0 = blk,             *ih1 = blk + 16384, *ihn = blk + 2 * 16384;
  const bf16 *hh0 = blk + 3 * 16384, *hh1 = blk + 4 * 16384, *hhn = blk + 5 * 16384;
  const bf16 *bih = wb + 217088, *bhh = wb + 217472;

  long r0 = mbase + lr;      if (r0 >= M) r0 = M - 1;
  long r1 = mbase + 16 + lr; if (r1 >= M) r1 = M - 1;

  // h fragments early (independent stream; covers HBM latency under pass1)
  bf16x8 hf[2][4];
#pragma unroll
  for (int kk = 0; kk < 4; ++kk) {
    hf[0][kk] = *(const bf16x8*)(hbp + r0 * 128 + kk * 32 + quad * 8);
    hf[1][kk] = *(const bf16x8*)(hbp + r1 * 128 + kk * 32 + quad * 8);
  }

  // ---- pass 1: a-tile (K=544) ----
  f32x4 acc[2][8];
#pragma unroll
  for (int i = 0; i < 2; ++i)
#pragma unroll
    for (int j = 0; j < 8; ++j) acc[i][j] = (f32x4){0.f, 0.f, 0.f, 0.f};
#pragma unroll
  for (int kk = 0; kk < 17; ++kk) {
    const int kc = kk * 32 + quad * 8;
    bf16x8 a0 = *(const bf16x8*)(big + r0 * 544 + kc);
    bf16x8 a1 = *(const bf16x8*)(big + r1 * 544 + kc);
#pragma unroll
    for (int ct = 0; ct < 8; ++ct) {
      bf16x8 b = *(const bf16x8*)(wcat + ((size_t)(kk * 8 + ct) * 64 + lane) * 8);
      acc[0][ct] = __builtin_amdgcn_mfma_f32_16x16x32_bf16(a0, b, acc[0][ct], 0, 0, 0);
      acc[1][ct] = __builtin_amdgcn_mfma_f32_16x16x32_bf16(a1, b, acc[1][ct], 0, 0, 0);
    }
  }
  // stage a-tile to LDS (wave-private rows; C/D layout transpose)
#pragma unroll
  for (int ct = 0; ct < 8; ++ct) {
    const int nl = ct * 16 + lr;
#pragma unroll
    for (int rt = 0; rt < 2; ++rt) {
      const int rowb = w * 32 + rt * 16 + quad * 4;
#pragma unroll
      for (int r = 0; r < 4; ++r)
        lds[(rowb + r) * 136 + nl] = (bf16)acc[rt][ct][r];
    }
  }
  // wave reads only its own rows back -> no barrier (same-wave DS in order)
  bf16x8 af[2][4];
#pragma unroll
  for (int kk = 0; kk < 4; ++kk) {
    af[0][kk] = *(const bf16x8*)(lds + (w * 32 + lr) * 136 + kk * 32 + quad * 8);
    af[1][kk] = *(const bf16x8*)(lds + (w * 32 + 16 + lr) * 136 + kk * 32 + quad * 8);
  }
  // overwrite own rows with the h-tile (row-major) for C/D-layout hv reads
#pragma unroll
  for (int kk = 0; kk < 4; ++kk) {
    *(bf16x8*)(lds + (w * 32 + lr) * 136 + kk * 32 + quad * 8)      = hf[0][kk];
    *(bf16x8*)(lds + (w * 32 + 16 + lr) * 136 + kk * 32 + quad * 8) = hf[1][kk];
  }

  // ---- gate GEMMs + GRU per 32-col chunk ----
#pragma unroll
  for (int cc = 0; cc < 4; ++cc) {
    f32x4 c[4][2][2];   // [slice][rt][cj]: s0=r, s1=z, s2=in, s3=hn
#pragma unroll
    for (int s = 0; s < 4; ++s)
#pragma unroll
      for (int i = 0; i < 2; ++i)
#pragma unroll
        for (int j = 0; j < 2; ++j) c[s][i][j] = (f32x4){0.f, 0.f, 0.f, 0.f};

#pragma unroll
    for (int kk = 0; kk < 4; ++kk) {
#pragma unroll
      for (int cj = 0; cj < 2; ++cj) {
        const int ct = cc * 2 + cj;
        const size_t wi = ((size_t)(kk * 8 + ct) * 64 + lane) * 8;
        bf16x8 b;
        b = *(const bf16x8*)(ih0 + wi);
        c[0][0][cj] = __builtin_amdgcn_mfma_f32_16x16x32_bf16(af[0][kk], b, c[0][0][cj], 0, 0, 0);
        c[0][1][cj] = __builtin_amdgcn_mfma_f32_16x16x32_bf16(af[1][kk], b, c[0][1][cj], 0, 0, 0);
        b = *(const bf16x8*)(hh0 + wi);
        c[0][0][cj] = __builtin_amdgcn_mfma_f32_16x16x32_bf16(hf[0][kk], b, c[0][0][cj], 0, 0, 0);
        c[0][1][cj] = __builtin_amdgcn_mfma_f32_16x16x32_bf16(hf[1][kk], b, c[0][1][cj], 0, 0, 0);
        b = *(const bf16x8*)(ih1 + wi);
        c[1][0][cj] = __builtin_amdgcn_mfma_f32_16x16x32_bf16(af[0][kk], b, c[1][0][cj], 0, 0, 0);
        c[1][1][cj] = __builtin_amdgcn_mfma_f32_16x16x32_bf16(af[1][kk], b, c[1][1][cj], 0, 0, 0);
        b = *(const bf16x8*)(hh1 + wi);
        c[1][0][cj] = __builtin_amdgcn_mfma_f32_16x16x32_bf16(hf[0][kk], b, c[1][0][cj], 0, 0, 0);
        c[1][1][cj] = __builtin_amdgcn_mfma_f32_16x16x32_bf16(hf[1][kk], b, c[1][1][cj], 0, 0, 0);
        b = *(const bf16x8*)(ihn + wi);
        c[2][0][cj] = __builtin_amdgcn_mfma_f32_16x16x32_bf16(af[0][kk], b, c[2][0][cj], 0, 0, 0);
        c[2][1][cj] = __builtin_amdgcn_mfma_f32_16x16x32_bf16(af[1][kk], b, c[2][1][cj], 0, 0, 0);
        b = *(const bf16x8*)(hhn + wi);
        c[3][0][cj] = __builtin_amdgcn_mfma_f32_16x16x32_bf16(hf[0][kk], b, c[3][0][cj], 0, 0, 0);
        c[3][1][cj] = __builtin_amdgcn_mfma_f32_16x16x32_bf16(hf[1][kk], b, c[3][1][cj], 0, 0, 0);
      }
    }
    // GRU nonlinearity in registers; hv from LDS; h' back into same slot
#pragma unroll
    for (int cj = 0; cj < 2; ++cj) {
      const int col = cc * 32 + cj * 16 + lr;
      const float br = (float)bih[col]       + (float)bhh[col];
      const float bz = (float)bih[128 + col] + (float)bhh[128 + col];
      const float bi = (float)bih[256 + col];
      const float bh = (float)bhh[256 + col];
#pragma unroll
      for (int rt = 0; rt < 2; ++rt) {
        const int rowb = w * 32 + rt * 16 + quad * 4;
#pragma unroll
        for (int r = 0; r < 4; ++r) {
          const int li = (rowb + r) * 136 + col;
          const float hv = (float)lds[li];
          const float rr = 1.f / (1.f + __expf(-(c[0][rt][cj][r] + br)));
          const float zz = 1.f / (1.f + __expf(-(c[1][rt][cj][r] + bz)));
          const float xn = c[2][rt][cj][r] + bi + rr * (c[3][rt][cj][r] + bh);
          const float e2 = __expf(2.f * xn);
          const float nn = 1.f - 2.f / (e2 + 1.f);   // tanh(xn)
          lds[li] = (bf16)((1.f - zz) * nn + zz * hv);
        }
      }
    }
  }

  __syncthreads();
  // coalesced h' store
  const int tr = threadIdx.x >> 4;
  const int tc = (threadIdx.x & 15) * 8;
#pragma unroll
  for (int i = 0; i < 8; ++i) {
    const int row = i * 16 + tr;
    const int grow = blockIdx.x * 128 + row;
    if (grow < M) {
      bf16x8 v = *(const bf16x8*)(lds + row * 136 + tc);
      *(bf16x8*)(hbp + (size_t)grow * 128 + tc) = v;
    }
  }
}

// ---------------------------------------------------------------------------
// dtype detect (bf16 features never have |x|>=256; fp32 low halves do)
// ---------------------------------------------------------------------------
__global__ __launch_bounds__(256) void detect_k(const unsigned short* __restrict__ f,
                                                int n16, int* __restrict__ flag)
{
  int i = blockIdx.x * 256 + threadIdx.x;
  int bad = 0;
  for (int j = i; j < n16; j += 256 * 1024) {
    int ex = (f[j] >> 7) & 0xFF;
    if (ex >= 0x87) bad = 1;
  }
  if (bad) atomicAdd(flag, 1);
}

__global__ __launch_bounds__(256) void feat_k(const void* __restrict__ src,
                                              bf16* __restrict__ hb, int n,
                                              const int* __restrict__ flag)
{
  int i = blockIdx.x * 256 + threadIdx.x;
  if (i >= n) return;
  if (*flag) hb[i] = (bf16)((const float*)src)[i];
  else       hb[i] = ((const bf16*)src)[i];
}

// ---------------------------------------------------------------------------
// weight canonicalize + swizzle.  wb layout (elements):
//   [0, 69632)        WcatX swz, NK=17: (n,k): k<512 -> W_et[k>>7][n][k&127],
//                     512..515 -> b_et[k-512][n], else 0
//   [69632 + blk*16384) 9 swz 128x128 blocks: ih0,ih1,ihn,hh0,hh1,hhn,iwa,iwb,jw
//   [217088) b_ih(384) b_hh(384) i_b(128) j_b(128)   -> total 218112
// ---------------------------------------------------------------------------
__global__ __launch_bounds__(256) void cvtw_k(
    const void* w_et, const void* b_et, const void* w_ih, const void* b_ih,
    const void* w_hh, const void* b_hh, const void* i_w, const void* i_b,
    const void* j_w, const void* j_b, bf16* __restrict__ wb,
    const int* __restrict__ flagp)
{
  int i = blockIdx.x * 256 + threadIdx.x;
  if (i >= 218112) return;
  const bool f32 = (*flagp != 0);
  auto rd = [&](const void* p, int idx) -> float {
    return f32 ? ((const float*)p)[idx] : (float)((const bf16*)p)[idx];
  };
  float v;
  if (i < 69632) {
    int e = i, j = e & 7, lane = (e >> 3) & 63, ct = (e >> 9) & 7, kk = e >> 12;
    int n = ct * 16 + (lane & 15), k = kk * 32 + (lane >> 4) * 8 + j;
    if (k < 512)      v = rd(w_et, (k >> 7) * 16384 + n * 128 + (k & 127));
    else if (k < 516) v = rd(b_et, (k - 512) * 128 + n);
    else              v = 0.f;
  } else if (i < 217088) {
    int blk = (i - 69632) >> 14, e = (i - 69632) & 16383;
    int j = e & 7, lane = (e >> 3) & 63, ct = (e >> 9) & 7, kk = e >> 12;
    int n = ct * 16 + (lane & 15), k = kk * 32 + (lane >> 4) * 8 + j;
    const void* src; int idx;
    switch (blk) {
      case 0: src = w_ih; idx = n * 128 + k; break;
      case 1: src = w_ih; idx = (128 + n) * 128 + k; break;
      case 2: src = w_ih; idx = (256 + n) * 128 + k; break;
      case 3: src = w_hh; idx = n * 128 + k; break;
      case 4: src = w_hh; idx = (128 + n) * 128 + k; break;
      case 5: src = w_hh; idx = (256 + n) * 128 + k; break;
      case 6: src = i_w;  idx = n * 256 + k; break;
      case 7: src = i_w;  idx = n * 256 + 128 + k; break;
      default: src = j_w; idx = n * 128 + k; break;
    }
    v = rd(src, idx);
  } else {
    int o = i - 217088;
    if (o < 384)      v = rd(b_ih, o);
    else if (o < 768) v = rd(b_hh, o - 384);
    else if (o < 896) v = rd(i_b, o - 768);
    else              v = rd(j_b, o - 896);
  }
  wb[i] = (bf16)v;
}

// ---------------------------------------------------------------------------
// CSR keyed by dst*4 + etype  (dst/etype constant across steps)
// ---------------------------------------------------------------------------
__global__ __launch_bounds__(256) void hist_k(const int* __restrict__ dst,
                                              const int* __restrict__ ety,
                                              int* __restrict__ deg, int E)
{
  int e = blockIdx.x * 256 + threadIdx.x;
  if (e < E) atomicAdd(&deg[dst[e] * 4 + ety[e]], 1);
}

__global__ __launch_bounds__(512) void scan1_k(const int* __restrict__ deg, int* __restrict__ rp,
                                               int* __restrict__ part, int n)
{
  __shared__ int buf[512];
  int i = blockIdx.x * 512 + threadIdx.x;
  int v = (i < n) ? deg[i] : 0;
  buf[threadIdx.x] = v;
  __syncthreads();
#pragma unroll
  for (int off = 1; off < 512; off <<= 1) {
    int t = 0;
    if (threadIdx.x >= off) t = buf[threadIdx.x - off];
    __syncthreads();
    buf[threadIdx.x] += t;
    __syncthreads();
  }
  if (i < n) rp[i] = buf[threadIdx.x] - v;
  if (threadIdx.x == 511) part[blockIdx.x] = buf[511];
}

__global__ __launch_bounds__(1024) void scan2_k(int* __restrict__ part, int nb, int* __restrict__ total)
{
  __shared__ int buf[1024];
  int t0 = threadIdx.x;
  int v = (t0 < nb) ? part[t0] : 0;
  buf[t0] = v;
  __syncthreads();
#pragma unroll
  for (int off = 1; off < 1024; off <<= 1) {
    int t = 0;
    if (t0 >= off) t = buf[t0 - off];
    __syncthreads();
    buf[t0] += t;
    __syncthreads();
  }
  if (t0 < nb) part[t0] = buf[t0] - v;
  if (t0 == 1023) *total = buf[1023];
}

__global__ __launch_bounds__(512) void scan3_k(int* __restrict__ rp, const int* __restrict__ part, int n)
{
  int i = blockIdx.x * 512 + threadIdx.x;
  if (i < n) rp[i] += part[blockIdx.x];
}

__global__ __launch_bounds__(256) void fill_k(const int* __restrict__ src, const int* __restrict__ dst,
                                              const int* __restrict__ ety, const int* __restrict__ rp,
                                              int* __restrict__ fil, int* __restrict__ bkt, int E)
{
  int e = blockIdx.x * 256 + threadIdx.x;
  if (e < E) {
    int key = dst[e] * 4 + ety[e];
    int pos = rp[key] + atomicAdd(&fil[key], 1);
    bkt[pos] = src[e];
  }
}

// ---------------------------------------------------------------------------
// aggregate raw h per (dst, etype) -> aggH[n, 544]:
//   cols k*128+d = sum of h[src][d] over etype-k in-edges; 512+k = deg_k; rest 0
// wave per node; lane owns 2 dims (one dword per edge-row read).
// Edge loop is batched 4-wide (clamped indices + predicated accumulate) so
// each wave keeps 4 independent row-gathers in flight instead of a serial
// bkt->h dependency chain per edge (agg was latency-bound: 23% HBM, 20% VALU).
// ---------------------------------------------------------------------------
__global__ __launch_bounds__(256) void agg_k(const bf16* __restrict__ hb,
                                             const int* __restrict__ rp,
                                             const int* __restrict__ bkt,
                                             bf16* __restrict__ aggH, int N)
{
  const int lane = threadIdx.x & 63;
  const int n = blockIdx.x * 4 + (threadIdx.x >> 6);
  if (n >= N) return;
  const unsigned* hp = (const unsigned*)hb;
  unsigned* outp = (unsigned*)aggH + (size_t)n * 272;
  int d0, d1, d2, d3;
  int prev = rp[n * 4];
#pragma unroll
  for (int k = 0; k < 4; ++k) {
    int nxt = rp[n * 4 + k + 1];
    const int last = nxt - 1;
    float a0 = 0.f, a1 = 0.f;
    for (int base = prev; base < nxt; base += 4) {
      const int i1 = base + 1, i2 = base + 2, i3 = base + 3;
      // batch the index loads (independent, uniform addresses)
      int b0 = bkt[base];
      int b1 = bkt[i1 < nxt ? i1 : last];
      int b2 = bkt[i2 < nxt ? i2 : last];
      int b3 = bkt[i3 < nxt ? i3 : last];
      // 4 independent coalesced 256B row-gathers in flight per wave
      unsigned u0 = hp[(size_t)b0 * 64 + lane];
      unsigned u1 = hp[(size_t)b1 * 64 + lane];
      unsigned u2 = hp[(size_t)b2 * 64 + lane];
      unsigned u3 = hp[(size_t)b3 * 64 + lane];
      BP t0, t1, t2, t3;
      t0.u = u0; t1.u = u1; t2.u = u2; t3.u = u3;
      a0 += (float)t0.b[0];
      a1 += (float)t0.b[1];
      a0 += (i1 < nxt) ? (float)t1.b[0] : 0.f;
      a1 += (i1 < nxt) ? (float)t1.b[1] : 0.f;
      a0 += (i2 < nxt) ? (float)t2.b[0] : 0.f;
      a1 += (i2 < nxt) ? (float)t2.b[1] : 0.f;
      a0 += (i3 < nxt) ? (float)t3.b[0] : 0.f;
      a1 += (i3 < nxt) ? (float)t3.b[1] : 0.f;
    }
    BP o; o.b[0] = (bf16)a0; o.b[1] = (bf16)a1;
    outp[k * 64 + lane] = o.u;
    int dk = nxt - prev;
    if (k == 0) d0 = dk; else if (k == 1) d1 = dk; else if (k == 2) d2 = dk; else d3 = dk;
    prev = nxt;
  }
  if (lane < 16) {
    BP o; o.b[0] = (bf16)0.f; o.b[1] = (bf16)0.f;
    if (lane == 0) { o.b[0] = (bf16)(float)d0; o.b[1] = (bf16)(float)d1; }
    if (lane == 1) { o.b[0] = (bf16)(float)d2; o.b[1] = (bf16)(float)d3; }
    outp[256 + lane] = o.u;
  }
}

// head: G[n,256] = [gl | u];  out = sigmoid(gl) * u
__global__ __launch_bounds__(256) void head_k(const bf16* __restrict__ G,
                                              void* __restrict__ out, int N,
                                              const int* __restrict__ flag)
{
  int i = blockIdx.x * 256 + threadIdx.x;    // over N*64
  if (i >= N * 64) return;
  int n = i >> 6, l = i & 63;
  const unsigned* g = (const unsigned*)G + (size_t)n * 128;
  BP gl, uu;
  gl.u = g[l]; uu.u = g[64 + l];
  float v0 = (float)uu.b[0] / (1.f + expf(-(float)gl.b[0]));
  float v1 = (float)uu.b[1] / (1.f + expf(-(float)gl.b[1]));
  if (*flag) {
    ((float*)out)[(size_t)n * 128 + 2 * l]     = v0;
    ((float*)out)[(size_t)n * 128 + 2 * l + 1] = v1;
  } else {
    BP o; o.b[0] = (bf16)v0; o.b[1] = (bf16)v1;
    ((unsigned*)out)[(size_t)n * 64 + l] = o.u;
  }
}

// ---------------------------------------------------------------------------
extern "C" void kernel_launch(void* const* d_in, const int* in_sizes, int n_in,
                              void* d_out, int out_size, void* d_ws, size_t ws_size,
                              hipStream_t stream)
{
  const void* feat = d_in[0];
  const int*  src  = (const int*)d_in[1];
  const int*  dst  = (const int*)d_in[2];
  const int*  ety  = (const int*)d_in[3];

  const int N = in_sizes[0] / 128;   // 100000
  const int E = in_sizes[1];         // 1600000
  const int total = N * 128;

  // ---- workspace (~145 MB) ----
  char* p = (char*)d_ws;
  auto alloc = [&](size_t bytes) -> char* {
    char* q = p;
    p += (bytes + 255) & ~(size_t)255;
    return q;
  };
  bf16* big  = (bf16*)alloc((size_t)N * 544 * 2);   // aggH [N,544] / head G [N,256]
  bf16* hb   = (bf16*)alloc((size_t)total * 2);     // h (bf16)
  bf16* wb   = (bf16*)alloc(218112 * 2);
  int*  rp   = (int*) alloc(((size_t)4 * N + 1) * 4);
  int*  deg  = (int*) alloc((size_t)4 * N * 4);     // reused as fill counters
  int*  bkt  = (int*) alloc((size_t)E * 4);
  int*  part = (int*) alloc(1024 * 4);
  int*  flag = (int*) alloc(64);

  // wb offsets
  const int oBlk = 69632;
  const bf16 *iwa = wb + oBlk + 6 * 16384, *iwb = wb + oBlk + 7 * 16384,
             *jw  = wb + oBlk + 8 * 16384;
  const bf16 *ib = wb + 217856, *jb = wb + 217984;

  const int gE  = (E + 255) / 256;
  const int gT  = (total + 255) / 256;
  const int gM  = (N + 127) / 128;
  const int n4  = 4 * N;
  const int gS  = (n4 + 511) / 512;
  const int gH  = (N * 64 + 255) / 256;

  // ---- dtype detect + canonicalize ----
  hipMemsetAsync(flag, 0, 4, stream);
  detect_k<<<1024, 256, 0, stream>>>((const unsigned short*)feat, 2000000, flag);
  feat_k<<<gT, 256, 0, stream>>>(feat, hb, total, flag);
  cvtw_k<<<(218112 + 255) / 256, 256, 0, stream>>>(
      d_in[4], d_in[5], d_in[6], d_in[7], d_in[8],
      d_in[9], d_in[10], d_in[11], d_in[12], d_in[13], wb, flag);

  // ---- CSR build ----
  hipMemsetAsync(deg, 0, (size_t)n4 * 4, stream);
  hist_k<<<gE, 256, 0, stream>>>(dst, ety, deg, E);
  scan1_k<<<gS, 512, 0, stream>>>(deg, rp, part, n4);
  scan2_k<<<1, 1024, 0, stream>>>(part, gS, rp + n4);
  scan3_k<<<gS, 512, 0, stream>>>(rp, part, n4);
  hipMemsetAsync(deg, 0, (size_t)n4 * 4, stream);
  fill_k<<<gE, 256, 0, stream>>>(src, dst, ety, rp, deg, bkt, E);

  // ---- head GEMM descriptors ----
  Desc4 Ph = {};
  Ph.d[0] = { hb, iwa, 128, feat, iwb, 128, ib, nullptr, 0,   2 };
  Ph.d[1] = { hb, jw,  128, nullptr, nullptr, 0, jb, nullptr, 128, 0 };

  for (int step = 0; step < 3; ++step) {
    agg_k<<<(N + 3) / 4, 256, 0, stream>>>(hb, rp, bkt, big, N);
    fused_k<<<gM, 256, 0, stream>>>(big, hb, wb, N);
  }

  // ---- head ----
  gemm_k<4><<<dim3(gM, 2), 256, 0, stream>>>(Ph, big, 256, N, flag);
  head_k<<<gH, 256, 0, stream>>>(big, d_out, N, flag);
}

// Round 4
// 989.822 us; speedup vs baseline: 1.4139x; 1.3078x over previous
//
#include <hip/hip_runtime.h>
#include <hip/hip_bf16.h>

typedef __bf16 bf16;
typedef __attribute__((ext_vector_type(8))) __bf16 bf16x8;
typedef __attribute__((ext_vector_type(4))) float f32x4;

union BP { unsigned u; bf16 b[2]; };

// ---------------------------------------------------------------------------
// Desc: one 128-output-col GEMM slice.  C[:, coff:coff+128] =
//   A1 @ swz(W1)^T (+ A2 @ swz(W2)^T) + b1 (+ b2)
// W pointers are PRE-SWIZZLED blocks: elem ((kk*8+ct)*64+lane)*8+j holds
// W[ct*16+(lane&15)][kk*32+(lane>>4)*8+j]  -> every B-load is a coalesced
// 1KB wave load.  a2mode: 0=none, 1=bf16, 2=dtype per *flagp (f32 if set).
// (Only the output head uses this now; step GEMMs+GRU live in fused_k.)
// ---------------------------------------------------------------------------
struct Desc {
  const void* A1; const bf16* W1; int lda1;
  const void* A2; const bf16* W2; int lda2;
  const bf16* b1; const bf16* b2;
  int coff; int a2mode;
};
struct Desc4 { Desc d[4]; };

// NK = number of 32-wide K chunks (4 -> K=128)
template<int NK>
__global__ __launch_bounds__(256) void gemm_k(Desc4 P, bf16* __restrict__ C, int ldc,
                                              int M, const int* __restrict__ flagp)
{
  const Desc d = P.d[blockIdx.y];
  const int lane = threadIdx.x & 63;
  const int w    = threadIdx.x >> 6;
  const int quad = lane >> 4;
  const int lr   = lane & 15;
  const int mbase = blockIdx.x * 128 + w * 32;

  __shared__ bf16 lds[128 * 136];   // padded stride 136 (272B rows, 16B aligned)

  f32x4 acc[2][8];
#pragma unroll
  for (int i = 0; i < 2; ++i)
#pragma unroll
    for (int j = 0; j < 8; ++j) acc[i][j] = (f32x4){0.f, 0.f, 0.f, 0.f};

  long r0 = mbase + lr;      if (r0 >= M) r0 = M - 1;
  long r1 = mbase + 16 + lr; if (r1 >= M) r1 = M - 1;

  // ---- A1 pass (A1 is always bf16) ----
  {
    const bf16* A = (const bf16*)d.A1;
    const int lda = d.lda1;
#pragma unroll
    for (int kk = 0; kk < NK; ++kk) {
      const int kc = kk * 32 + quad * 8;
      bf16x8 a0 = *(const bf16x8*)(A + r0 * lda + kc);
      bf16x8 a1 = *(const bf16x8*)(A + r1 * lda + kc);
#pragma unroll
      for (int ct = 0; ct < 8; ++ct) {
        bf16x8 b = *(const bf16x8*)(d.W1 + ((size_t)(kk * 8 + ct) * 64 + lane) * 8);
        acc[0][ct] = __builtin_amdgcn_mfma_f32_16x16x32_bf16(a0, b, acc[0][ct], 0, 0, 0);
        acc[1][ct] = __builtin_amdgcn_mfma_f32_16x16x32_bf16(a1, b, acc[1][ct], 0, 0, 0);
      }
    }
  }
  // ---- A2 pass ----
  if (d.a2mode != 0) {
    const int lda = d.lda2;
    const bool f32 = (d.a2mode == 2) && (*flagp != 0);
    if (f32) {
      const float* A = (const float*)d.A2;
#pragma unroll
      for (int kk = 0; kk < NK; ++kk) {
        const int kc = kk * 32 + quad * 8;
        f32x4 x0 = *(const f32x4*)(A + r0 * lda + kc);
        f32x4 x1 = *(const f32x4*)(A + r0 * lda + kc + 4);
        f32x4 y0 = *(const f32x4*)(A + r1 * lda + kc);
        f32x4 y1 = *(const f32x4*)(A + r1 * lda + kc + 4);
        bf16x8 a0, a1;
#pragma unroll
        for (int i = 0; i < 4; ++i) {
          a0[i] = (bf16)x0[i]; a0[i + 4] = (bf16)x1[i];
          a1[i] = (bf16)y0[i]; a1[i + 4] = (bf16)y1[i];
        }
#pragma unroll
        for (int ct = 0; ct < 8; ++ct) {
          bf16x8 b = *(const bf16x8*)(d.W2 + ((size_t)(kk * 8 + ct) * 64 + lane) * 8);
          acc[0][ct] = __builtin_amdgcn_mfma_f32_16x16x32_bf16(a0, b, acc[0][ct], 0, 0, 0);
          acc[1][ct] = __builtin_amdgcn_mfma_f32_16x16x32_bf16(a1, b, acc[1][ct], 0, 0, 0);
        }
      }
    } else {
      const bf16* A = (const bf16*)d.A2;
#pragma unroll
      for (int kk = 0; kk < NK; ++kk) {
        const int kc = kk * 32 + quad * 8;
        bf16x8 a0 = *(const bf16x8*)(A + r0 * lda + kc);
        bf16x8 a1 = *(const bf16x8*)(A + r1 * lda + kc);
#pragma unroll
        for (int ct = 0; ct < 8; ++ct) {
          bf16x8 b = *(const bf16x8*)(d.W2 + ((size_t)(kk * 8 + ct) * 64 + lane) * 8);
          acc[0][ct] = __builtin_amdgcn_mfma_f32_16x16x32_bf16(a0, b, acc[0][ct], 0, 0, 0);
          acc[1][ct] = __builtin_amdgcn_mfma_f32_16x16x32_bf16(a1, b, acc[1][ct], 0, 0, 0);
        }
      }
    }
  }

  // ---- epilogue: acc -> LDS (C/D layout: col=lr, row16 = quad*4+reg) ----
#pragma unroll
  for (int ct = 0; ct < 8; ++ct) {
    const int nl = ct * 16 + lr;
    float bv = 0.f;
    if (d.b1) bv += (float)d.b1[nl];
    if (d.b2) bv += (float)d.b2[nl];
#pragma unroll
    for (int rt = 0; rt < 2; ++rt) {
      const int rowb = w * 32 + rt * 16 + quad * 4;
#pragma unroll
      for (int r = 0; r < 4; ++r)
        lds[(rowb + r) * 136 + nl] = (bf16)(acc[rt][ct][r] + bv);
    }
  }
  __syncthreads();
  // coalesced readback + store: 16 threads cover one 256B row segment
  const int tr = threadIdx.x >> 4;          // 0..15
  const int tc = (threadIdx.x & 15) * 8;    // col
#pragma unroll
  for (int i = 0; i < 8; ++i) {
    const int row = i * 16 + tr;
    const int grow = blockIdx.x * 128 + row;
    if (grow < M) {
      bf16x8 v = *(const bf16x8*)(lds + row * 136 + tc);
      *(bf16x8*)(C + (size_t)grow * ldc + d.coff + tc) = v;
    }
  }
}

// ---------------------------------------------------------------------------
// fully-fused step kernel: a = aggH @ Wcat  ->  GRU gate GEMMs  ->  GRU
// nonlinearity -> h' in place to hb.
// ROUND-4 CHANGE: explicit depth-2 rotating prefetch for ALL global B/A
// loads.  Round-3 counters (VGPR 92, MfmaUtil 6.4%, 99% of wave time in
// vmcnt waits on ~360 serial ~600cy loads) showed the compiler does NOT
// software-pipeline global loads on its own.  The named 2-slot rotation
// (consume buf[k&1], refill with k+2) forces ~10 loads in flight per wave.
// Gate phase restructured to 16-col chunks so its accumulator is c[4][2]
// (32 regs), making room for the Gb[2][6] weight pipeline (48 regs).
// Per-phase budget ~160 VGPR -> 2-3 waves/SIMD with real per-wave ILP.
// ---------------------------------------------------------------------------
__global__ __launch_bounds__(256) void fused_k(const bf16* __restrict__ big,
                                               bf16* __restrict__ hbp,
                                               const bf16* __restrict__ wb,
                                               int M)
{
  const int lane = threadIdx.x & 63;
  const int w    = threadIdx.x >> 6;
  const int quad = lane >> 4;
  const int lr   = lane & 15;
  const int mbase = blockIdx.x * 128 + w * 32;

  __shared__ bf16 lds[128 * 136];

  const bf16* wcat = wb;
  const bf16* blk  = wb + 69632;
  const bf16 *ih0 = blk,             *ih1 = blk + 16384, *ihn = blk + 2 * 16384;
  const bf16 *hh0 = blk + 3 * 16384, *hh1 = blk + 4 * 16384, *hhn = blk + 5 * 16384;
  const bf16 *bih = wb + 217088, *bhh = wb + 217472;

  long r0 = mbase + lr;      if (r0 >= M) r0 = M - 1;
  long r1 = mbase + 16 + lr; if (r1 >= M) r1 = M - 1;

  // ---- pass 1: a-tile (K=544), depth-2 pipelined ----
  f32x4 acc[2][8];
#pragma unroll
  for (int i = 0; i < 2; ++i)
#pragma unroll
    for (int j = 0; j < 8; ++j) acc[i][j] = (f32x4){0.f, 0.f, 0.f, 0.f};

  bf16x8 Bb[2][8];
  bf16x8 Ab[2][2];
  // preload kk=0,1
#pragma unroll
  for (int q = 0; q < 2; ++q) {
    const int kc = q * 32 + quad * 8;
    Ab[q][0] = *(const bf16x8*)(big + r0 * 544 + kc);
    Ab[q][1] = *(const bf16x8*)(big + r1 * 544 + kc);
#pragma unroll
    for (int ct = 0; ct < 8; ++ct)
      Bb[q][ct] = *(const bf16x8*)(wcat + ((size_t)(q * 8 + ct) * 64 + lane) * 8);
  }
#pragma unroll
  for (int kk = 0; kk < 17; ++kk) {
    const int p = kk & 1;
#pragma unroll
    for (int ct = 0; ct < 8; ++ct) {
      acc[0][ct] = __builtin_amdgcn_mfma_f32_16x16x32_bf16(Ab[p][0], Bb[p][ct], acc[0][ct], 0, 0, 0);
      acc[1][ct] = __builtin_amdgcn_mfma_f32_16x16x32_bf16(Ab[p][1], Bb[p][ct], acc[1][ct], 0, 0, 0);
    }
    if (kk + 2 < 17) {
      const int k2 = kk + 2;
      const int kc = k2 * 32 + quad * 8;
      Ab[p][0] = *(const bf16x8*)(big + r0 * 544 + kc);
      Ab[p][1] = *(const bf16x8*)(big + r1 * 544 + kc);
#pragma unroll
      for (int ct = 0; ct < 8; ++ct)
        Bb[p][ct] = *(const bf16x8*)(wcat + ((size_t)(k2 * 8 + ct) * 64 + lane) * 8);
    }
  }

  // h fragments (after pass1 so pass1 keeps its register budget)
  bf16x8 hf[2][4];
#pragma unroll
  for (int kk = 0; kk < 4; ++kk) {
    hf[0][kk] = *(const bf16x8*)(hbp + r0 * 128 + kk * 32 + quad * 8);
    hf[1][kk] = *(const bf16x8*)(hbp + r1 * 128 + kk * 32 + quad * 8);
  }

  // stage a-tile to LDS (wave-private rows; C/D layout transpose)
#pragma unroll
  for (int ct = 0; ct < 8; ++ct) {
    const int nl = ct * 16 + lr;
#pragma unroll
    for (int rt = 0; rt < 2; ++rt) {
      const int rowb = w * 32 + rt * 16 + quad * 4;
#pragma unroll
      for (int r = 0; r < 4; ++r)
        lds[(rowb + r) * 136 + nl] = (bf16)acc[rt][ct][r];
    }
  }
  // wave reads only its own rows back -> no barrier (same-wave DS in order)
  bf16x8 af[2][4];
#pragma unroll
  for (int kk = 0; kk < 4; ++kk) {
    af[0][kk] = *(const bf16x8*)(lds + (w * 32 + lr) * 136 + kk * 32 + quad * 8);
    af[1][kk] = *(const bf16x8*)(lds + (w * 32 + 16 + lr) * 136 + kk * 32 + quad * 8);
  }
  // overwrite own rows with the h-tile (row-major) for C/D-layout hv reads
#pragma unroll
  for (int kk = 0; kk < 4; ++kk) {
    *(bf16x8*)(lds + (w * 32 + lr) * 136 + kk * 32 + quad * 8)      = hf[0][kk];
    *(bf16x8*)(lds + (w * 32 + 16 + lr) * 136 + kk * 32 + quad * 8) = hf[1][kk];
  }

  // ---- gate GEMMs + GRU per 16-col chunk, depth-2 pipelined weights ----
  // chunk ch = (cc<<1)|cj covers cols [ch*16, ch*16+16); group G = ch*4+kk.
  bf16x8 Gb[2][6];
#pragma unroll
  for (int q = 0; q < 2; ++q) {
    // G = q -> ch=0 (ct=0), kk=q
    const size_t wi = ((size_t)(q * 8 + 0) * 64 + lane) * 8;
    Gb[q][0] = *(const bf16x8*)(ih0 + wi);
    Gb[q][1] = *(const bf16x8*)(hh0 + wi);
    Gb[q][2] = *(const bf16x8*)(ih1 + wi);
    Gb[q][3] = *(const bf16x8*)(hh1 + wi);
    Gb[q][4] = *(const bf16x8*)(ihn + wi);
    Gb[q][5] = *(const bf16x8*)(hhn + wi);
  }

#pragma unroll
  for (int ch = 0; ch < 8; ++ch) {
    const int cc = ch >> 1, cj = ch & 1;
    f32x4 c[4][2];   // [slice][rt]: s0=r, s1=z, s2=in, s3=hn
#pragma unroll
    for (int s = 0; s < 4; ++s)
#pragma unroll
      for (int i = 0; i < 2; ++i) c[s][i] = (f32x4){0.f, 0.f, 0.f, 0.f};

#pragma unroll
    for (int kk = 0; kk < 4; ++kk) {
      const int G = ch * 4 + kk;
      const int p = G & 1;
      c[0][0] = __builtin_amdgcn_mfma_f32_16x16x32_bf16(af[0][kk], Gb[p][0], c[0][0], 0, 0, 0);
      c[0][1] = __builtin_amdgcn_mfma_f32_16x16x32_bf16(af[1][kk], Gb[p][0], c[0][1], 0, 0, 0);
      c[0][0] = __builtin_amdgcn_mfma_f32_16x16x32_bf16(hf[0][kk], Gb[p][1], c[0][0], 0, 0, 0);
      c[0][1] = __builtin_amdgcn_mfma_f32_16x16x32_bf16(hf[1][kk], Gb[p][1], c[0][1], 0, 0, 0);
      c[1][0] = __builtin_amdgcn_mfma_f32_16x16x32_bf16(af[0][kk], Gb[p][2], c[1][0], 0, 0, 0);
      c[1][1] = __builtin_amdgcn_mfma_f32_16x16x32_bf16(af[1][kk], Gb[p][2], c[1][1], 0, 0, 0);
      c[1][0] = __builtin_amdgcn_mfma_f32_16x16x32_bf16(hf[0][kk], Gb[p][3], c[1][0], 0, 0, 0);
      c[1][1] = __builtin_amdgcn_mfma_f32_16x16x32_bf16(hf[1][kk], Gb[p][3], c[1][1], 0, 0, 0);
      c[2][0] = __builtin_amdgcn_mfma_f32_16x16x32_bf16(af[0][kk], Gb[p][4], c[2][0], 0, 0, 0);
      c[2][1] = __builtin_amdgcn_mfma_f32_16x16x32_bf16(af[1][kk], Gb[p][4], c[2][1], 0, 0, 0);
      c[3][0] = __builtin_amdgcn_mfma_f32_16x16x32_bf16(hf[0][kk], Gb[p][5], c[3][0], 0, 0, 0);
      c[3][1] = __builtin_amdgcn_mfma_f32_16x16x32_bf16(hf[1][kk], Gb[p][5], c[3][1], 0, 0, 0);
      // prefetch group G+2 into the slot just consumed
      if (G + 2 < 32) {
        const int G2 = G + 2;
        const int ch2 = G2 >> 2, kk2 = G2 & 3;
        const int ct2 = ch2;            // ct = (cc2<<1)|cj2 = ch2
        const size_t wi2 = ((size_t)(kk2 * 8 + ct2) * 64 + lane) * 8;
        Gb[p][0] = *(const bf16x8*)(ih0 + wi2);
        Gb[p][1] = *(const bf16x8*)(hh0 + wi2);
        Gb[p][2] = *(const bf16x8*)(ih1 + wi2);
        Gb[p][3] = *(const bf16x8*)(hh1 + wi2);
        Gb[p][4] = *(const bf16x8*)(ihn + wi2);
        Gb[p][5] = *(const bf16x8*)(hhn + wi2);
      }
    }
    // GRU nonlinearity in registers; hv from LDS; h' back into same slot
    {
      const int col = ch * 16 + lr;
      const float br = (float)bih[col]       + (float)bhh[col];
      const float bz = (float)bih[128 + col] + (float)bhh[128 + col];
      const float bi = (float)bih[256 + col];
      const float bh = (float)bhh[256 + col];
#pragma unroll
      for (int rt = 0; rt < 2; ++rt) {
        const int rowb = w * 32 + rt * 16 + quad * 4;
#pragma unroll
        for (int r = 0; r < 4; ++r) {
          const int li = (rowb + r) * 136 + col;
          const float hv = (float)lds[li];
          const float rr = 1.f / (1.f + __expf(-(c[0][rt][r] + br)));
          const float zz = 1.f / (1.f + __expf(-(c[1][rt][r] + bz)));
          const float xn = c[2][rt][r] + bi + rr * (c[3][rt][r] + bh);
          const float e2 = __expf(2.f * xn);
          const float nn = 1.f - 2.f / (e2 + 1.f);   // tanh(xn)
          lds[li] = (bf16)((1.f - zz) * nn + zz * hv);
        }
      }
    }
  }

  __syncthreads();
  // coalesced h' store
  const int tr = threadIdx.x >> 4;
  const int tc = (threadIdx.x & 15) * 8;
#pragma unroll
  for (int i = 0; i < 8; ++i) {
    const int row = i * 16 + tr;
    const int grow = blockIdx.x * 128 + row;
    if (grow < M) {
      bf16x8 v = *(const bf16x8*)(lds + row * 136 + tc);
      *(bf16x8*)(hbp + (size_t)grow * 128 + tc) = v;
    }
  }
}

// ---------------------------------------------------------------------------
// dtype detect (bf16 features never have |x|>=256; fp32 low halves do)
// ---------------------------------------------------------------------------
__global__ __launch_bounds__(256) void detect_k(const unsigned short* __restrict__ f,
                                                int n16, int* __restrict__ flag)
{
  int i = blockIdx.x * 256 + threadIdx.x;
  int bad = 0;
  for (int j = i; j < n16; j += 256 * 1024) {
    int ex = (f[j] >> 7) & 0xFF;
    if (ex >= 0x87) bad = 1;
  }
  if (bad) atomicAdd(flag, 1);
}

__global__ __launch_bounds__(256) void feat_k(const void* __restrict__ src,
                                              bf16* __restrict__ hb, int n,
                                              const int* __restrict__ flag)
{
  int i = blockIdx.x * 256 + threadIdx.x;
  if (i >= n) return;
  if (*flag) hb[i] = (bf16)((const float*)src)[i];
  else       hb[i] = ((const bf16*)src)[i];
}

// ---------------------------------------------------------------------------
// weight canonicalize + swizzle.  wb layout (elements):
//   [0, 69632)        WcatX swz, NK=17: (n,k): k<512 -> W_et[k>>7][n][k&127],
//                     512..515 -> b_et[k-512][n], else 0
//   [69632 + blk*16384) 9 swz 128x128 blocks: ih0,ih1,ihn,hh0,hh1,hhn,iwa,iwb,jw
//   [217088) b_ih(384) b_hh(384) i_b(128) j_b(128)   -> total 218112
// ---------------------------------------------------------------------------
__global__ __launch_bounds__(256) void cvtw_k(
    const void* w_et, const void* b_et, const void* w_ih, const void* b_ih,
    const void* w_hh, const void* b_hh, const void* i_w, const void* i_b,
    const void* j_w, const void* j_b, bf16* __restrict__ wb,
    const int* __restrict__ flagp)
{
  int i = blockIdx.x * 256 + threadIdx.x;
  if (i >= 218112) return;
  const bool f32 = (*flagp != 0);
  auto rd = [&](const void* p, int idx) -> float {
    return f32 ? ((const float*)p)[idx] : (float)((const bf16*)p)[idx];
  };
  float v;
  if (i < 69632) {
    int e = i, j = e & 7, lane = (e >> 3) & 63, ct = (e >> 9) & 7, kk = e >> 12;
    int n = ct * 16 + (lane & 15), k = kk * 32 + (lane >> 4) * 8 + j;
    if (k < 512)      v = rd(w_et, (k >> 7) * 16384 + n * 128 + (k & 127));
    else if (k < 516) v = rd(b_et, (k - 512) * 128 + n);
    else              v = 0.f;
  } else if (i < 217088) {
    int blk = (i - 69632) >> 14, e = (i - 69632) & 16383;
    int j = e & 7, lane = (e >> 3) & 63, ct = (e >> 9) & 7, kk = e >> 12;
    int n = ct * 16 + (lane & 15), k = kk * 32 + (lane >> 4) * 8 + j;
    const void* src; int idx;
    switch (blk) {
      case 0: src = w_ih; idx = n * 128 + k; break;
      case 1: src = w_ih; idx = (128 + n) * 128 + k; break;
      case 2: src = w_ih; idx = (256 + n) * 128 + k; break;
      case 3: src = w_hh; idx = n * 128 + k; break;
      case 4: src = w_hh; idx = (128 + n) * 128 + k; break;
      case 5: src = w_hh; idx = (256 + n) * 128 + k; break;
      case 6: src = i_w;  idx = n * 256 + k; break;
      case 7: src = i_w;  idx = n * 256 + 128 + k; break;
      default: src = j_w; idx = n * 128 + k; break;
    }
    v = rd(src, idx);
  } else {
    int o = i - 217088;
    if (o < 384)      v = rd(b_ih, o);
    else if (o < 768) v = rd(b_hh, o - 384);
    else if (o < 896) v = rd(i_b, o - 768);
    else              v = rd(j_b, o - 896);
  }
  wb[i] = (bf16)v;
}

// ---------------------------------------------------------------------------
// CSR keyed by dst*4 + etype  (dst/etype constant across steps)
// ---------------------------------------------------------------------------
__global__ __launch_bounds__(256) void hist_k(const int* __restrict__ dst,
                                              const int* __restrict__ ety,
                                              int* __restrict__ deg, int E)
{
  int e = blockIdx.x * 256 + threadIdx.x;
  if (e < E) atomicAdd(&deg[dst[e] * 4 + ety[e]], 1);
}

__global__ __launch_bounds__(512) void scan1_k(const int* __restrict__ deg, int* __restrict__ rp,
                                               int* __restrict__ part, int n)
{
  __shared__ int buf[512];
  int i = blockIdx.x * 512 + threadIdx.x;
  int v = (i < n) ? deg[i] : 0;
  buf[threadIdx.x] = v;
  __syncthreads();
#pragma unroll
  for (int off = 1; off < 512; off <<= 1) {
    int t = 0;
    if (threadIdx.x >= off) t = buf[threadIdx.x - off];
    __syncthreads();
    buf[threadIdx.x] += t;
    __syncthreads();
  }
  if (i < n) rp[i] = buf[threadIdx.x] - v;
  if (threadIdx.x == 511) part[blockIdx.x] = buf[511];
}

__global__ __launch_bounds__(1024) void scan2_k(int* __restrict__ part, int nb, int* __restrict__ total)
{
  __shared__ int buf[1024];
  int t0 = threadIdx.x;
  int v = (t0 < nb) ? part[t0] : 0;
  buf[t0] = v;
  __syncthreads();
#pragma unroll
  for (int off = 1; off < 1024; off <<= 1) {
    int t = 0;
    if (t0 >= off) t = buf[t0 - off];
    __syncthreads();
    buf[t0] += t;
    __syncthreads();
  }
  if (t0 < nb) part[t0] = buf[t0] - v;
  if (t0 == 1023) *total = buf[1023];
}

__global__ __launch_bounds__(512) void scan3_k(int* __restrict__ rp, const int* __restrict__ part, int n)
{
  int i = blockIdx.x * 512 + threadIdx.x;
  if (i < n) rp[i] += part[blockIdx.x];
}

__global__ __launch_bounds__(256) void fill_k(const int* __restrict__ src, const int* __restrict__ dst,
                                              const int* __restrict__ ety, const int* __restrict__ rp,
                                              int* __restrict__ fil, int* __restrict__ bkt, int E)
{
  int e = blockIdx.x * 256 + threadIdx.x;
  if (e < E) {
    int key = dst[e] * 4 + ety[e];
    int pos = rp[key] + atomicAdd(&fil[key], 1);
    bkt[pos] = src[e];
  }
}

// ---------------------------------------------------------------------------
// aggregate raw h per (dst, etype) -> aggH[n, 544]:
//   cols k*128+d = sum of h[src][d] over etype-k in-edges; 512+k = deg_k; rest 0
// wave per node; lane owns 2 dims (one dword per edge-row read).
// Edge loop is batched 4-wide (clamped indices + predicated accumulate) so
// each wave keeps 4 independent row-gathers in flight instead of a serial
// bkt->h dependency chain per edge (agg was latency-bound: 23% HBM, 20% VALU).
// ---------------------------------------------------------------------------
__global__ __launch_bounds__(256) void agg_k(const bf16* __restrict__ hb,
                                             const int* __restrict__ rp,
                                             const int* __restrict__ bkt,
                                             bf16* __restrict__ aggH, int N)
{
  const int lane = threadIdx.x & 63;
  const int n = blockIdx.x * 4 + (threadIdx.x >> 6);
  if (n >= N) return;
  const unsigned* hp = (const unsigned*)hb;
  unsigned* outp = (unsigned*)aggH + (size_t)n * 272;
  int d0, d1, d2, d3;
  int prev = rp[n * 4];
#pragma unroll
  for (int k = 0; k < 4; ++k) {
    int nxt = rp[n * 4 + k + 1];
    const int last = nxt - 1;
    float a0 = 0.f, a1 = 0.f;
    for (int base = prev; base < nxt; base += 4) {
      const int i1 = base + 1, i2 = base + 2, i3 = base + 3;
      // batch the index loads (independent, uniform addresses)
      int b0 = bkt[base];
      int b1 = bkt[i1 < nxt ? i1 : last];
      int b2 = bkt[i2 < nxt ? i2 : last];
      int b3 = bkt[i3 < nxt ? i3 : last];
      // 4 independent coalesced 256B row-gathers in flight per wave
      unsigned u0 = hp[(size_t)b0 * 64 + lane];
      unsigned u1 = hp[(size_t)b1 * 64 + lane];
      unsigned u2 = hp[(size_t)b2 * 64 + lane];
      unsigned u3 = hp[(size_t)b3 * 64 + lane];
      BP t0, t1, t2, t3;
      t0.u = u0; t1.u = u1; t2.u = u2; t3.u = u3;
      a0 += (float)t0.b[0];
      a1 += (float)t0.b[1];
      a0 += (i1 < nxt) ? (float)t1.b[0] : 0.f;
      a1 += (i1 < nxt) ? (float)t1.b[1] : 0.f;
      a0 += (i2 < nxt) ? (float)t2.b[0] : 0.f;
      a1 += (i2 < nxt) ? (float)t2.b[1] : 0.f;
      a0 += (i3 < nxt) ? (float)t3.b[0] : 0.f;
      a1 += (i3 < nxt) ? (float)t3.b[1] : 0.f;
    }
    BP o; o.b[0] = (bf16)a0; o.b[1] = (bf16)a1;
    outp[k * 64 + lane] = o.u;
    int dk = nxt - prev;
    if (k == 0) d0 = dk; else if (k == 1) d1 = dk; else if (k == 2) d2 = dk; else d3 = dk;
    prev = nxt;
  }
  if (lane < 16) {
    BP o; o.b[0] = (bf16)0.f; o.b[1] = (bf16)0.f;
    if (lane == 0) { o.b[0] = (bf16)(float)d0; o.b[1] = (bf16)(float)d1; }
    if (lane == 1) { o.b[0] = (bf16)(float)d2; o.b[1] = (bf16)(float)d3; }
    outp[256 + lane] = o.u;
  }
}

// head: G[n,256] = [gl | u];  out = sigmoid(gl) * u
__global__ __launch_bounds__(256) void head_k(const bf16* __restrict__ G,
                                              void* __restrict__ out, int N,
                                              const int* __restrict__ flag)
{
  int i = blockIdx.x * 256 + threadIdx.x;    // over N*64
  if (i >= N * 64) return;
  int n = i >> 6, l = i & 63;
  const unsigned* g = (const unsigned*)G + (size_t)n * 128;
  BP gl, uu;
  gl.u = g[l]; uu.u = g[64 + l];
  float v0 = (float)uu.b[0] / (1.f + expf(-(float)gl.b[0]));
  float v1 = (float)uu.b[1] / (1.f + expf(-(float)gl.b[1]));
  if (*flag) {
    ((float*)out)[(size_t)n * 128 + 2 * l]     = v0;
    ((float*)out)[(size_t)n * 128 + 2 * l + 1] = v1;
  } else {
    BP o; o.b[0] = (bf16)v0; o.b[1] = (bf16)v1;
    ((unsigned*)out)[(size_t)n * 64 + l] = o.u;
  }
}

// ---------------------------------------------------------------------------
extern "C" void kernel_launch(void* const* d_in, const int* in_sizes, int n_in,
                              void* d_out, int out_size, void* d_ws, size_t ws_size,
                              hipStream_t stream)
{
  const void* feat = d_in[0];
  const int*  src  = (const int*)d_in[1];
  const int*  dst  = (const int*)d_in[2];
  const int*  ety  = (const int*)d_in[3];

  const int N = in_sizes[0] / 128;   // 100000
  const int E = in_sizes[1];         // 1600000
  const int total = N * 128;

  // ---- workspace (~145 MB) ----
  char* p = (char*)d_ws;
  auto alloc = [&](size_t bytes) -> char* {
    char* q = p;
    p += (bytes + 255) & ~(size_t)255;
    return q;
  };
  bf16* big  = (bf16*)alloc((size_t)N * 544 * 2);   // aggH [N,544] / head G [N,256]
  bf16* hb   = (bf16*)alloc((size_t)total * 2);     // h (bf16)
  bf16* wb   = (bf16*)alloc(218112 * 2);
  int*  rp   = (int*) alloc(((size_t)4 * N + 1) * 4);
  int*  deg  = (int*) alloc((size_t)4 * N * 4);     // reused as fill counters
  int*  bkt  = (int*) alloc((size_t)E * 4);
  int*  part = (int*) alloc(1024 * 4);
  int*  flag = (int*) alloc(64);

  // wb offsets
  const int oBlk = 69632;
  const bf16 *iwa = wb + oBlk + 6 * 16384, *iwb = wb + oBlk + 7 * 16384,
             *jw  = wb + oBlk + 8 * 16384;
  const bf16 *ib = wb + 217856, *jb = wb + 217984;

  const int gE  = (E + 255) / 256;
  const int gT  = (total + 255) / 256;
  const int gM  = (N + 127) / 128;
  const int n4  = 4 * N;
  const int gS  = (n4 + 511) / 512;
  const int gH  = (N * 64 + 255) / 256;

  // ---- dtype detect + canonicalize ----
  hipMemsetAsync(flag, 0, 4, stream);
  detect_k<<<1024, 256, 0, stream>>>((const unsigned short*)feat, 2000000, flag);
  feat_k<<<gT, 256, 0, stream>>>(feat, hb, total, flag);
  cvtw_k<<<(218112 + 255) / 256, 256, 0, stream>>>(
      d_in[4], d_in[5], d_in[6], d_in[7], d_in[8],
      d_in[9], d_in[10], d_in[11], d_in[12], d_in[13], wb, flag);

  // ---- CSR build ----
  hipMemsetAsync(deg, 0, (size_t)n4 * 4, stream);
  hist_k<<<gE, 256, 0, stream>>>(dst, ety, deg, E);
  scan1_k<<<gS, 512, 0, stream>>>(deg, rp, part, n4);
  scan2_k<<<1, 1024, 0, stream>>>(part, gS, rp + n4);
  scan3_k<<<gS, 512, 0, stream>>>(rp, part, n4);
  hipMemsetAsync(deg, 0, (size_t)n4 * 4, stream);
  fill_k<<<gE, 256, 0, stream>>>(src, dst, ety, rp, deg, bkt, E);

  // ---- head GEMM descriptors ----
  Desc4 Ph = {};
  Ph.d[0] = { hb, iwa, 128, feat, iwb, 128, ib, nullptr, 0,   2 };
  Ph.d[1] = { hb, jw,  128, nullptr, nullptr, 0, jb, nullptr, 128, 0 };

  for (int step = 0; step < 3; ++step) {
    agg_k<<<(N + 3) / 4, 256, 0, stream>>>(hb, rp, bkt, big, N);
    fused_k<<<gM, 256, 0, stream>>>(big, hb, wb, N);
  }

  // ---- head ----
  gemm_k<4><<<dim3(gM, 2), 256, 0, stream>>>(Ph, big, 256, N, flag);
  head_k<<<gH, 256, 0, stream>>>(big, d_out, N, flag);
}